// Round 7
// baseline (600.567 us; speedup 1.0000x reference)
//
#include <hip/hip_runtime.h>
#include <stdint.h>

#define NDIM 64
#define SCAN_ELEMS 2048   // elements per scan block (256 thr x 8)
#define NCHK 16           // edge chunks
#define NGRP 8            // node-range groups
#define RMAX 6272         // max nodes per group (ceil(50000/8)=6250)

// ---------------- weight transpose (k-major) ----------------
__global__ __launch_bounds__(256) void transpose_kernel(
    const float* __restrict__ fw, const float* __restrict__ rootw,
    const float* __restrict__ lin1, const float* __restrict__ lin2,
    float* __restrict__ fwT, float* __restrict__ wrT,
    float* __restrict__ w1T, float* __restrict__ w2T) {
  int e = blockIdx.x * 256 + threadIdx.x;
  if (e < 16384) {
    int o = e >> 8, k = e & 255;
    fwT[k * 64 + o] = fw[e];
  }
  int e2 = e - 16384;
  if (e2 >= 0 && e2 < 12288) {
    int l = e2 >> 12, r = e2 & 4095;
    int o = r >> 6, k = r & 63;
    size_t t = (size_t)l * 4096 + k * 64 + o;
    wrT[t] = rootw[e2];
    w1T[t] = lin1[e2];
    w2T[t] = lin2[e2];
  }
}

// ---------------- CSR build: atomic-free chunked counting sort ----------------
__global__ __launch_bounds__(256) void hist_kernel(
    const int* __restrict__ src, const int* __restrict__ dst,
    int* __restrict__ Hd, int* __restrict__ Hs, int E, int N, int chunk) {
  int c = blockIdx.x, g = blockIdx.y;
  int lo = (int)((long long)N * g / NGRP);
  int hi = (int)((long long)N * (g + 1) / NGRP);
  int range = hi - lo;
  __shared__ int cntd[RMAX];
  __shared__ int cnts[RMAX];
  for (int i = threadIdx.x; i < range; i += 256) { cntd[i] = 0; cnts[i] = 0; }
  __syncthreads();
  int e0 = c * chunk, e1 = min(E, e0 + chunk);
  for (int e = e0 + (int)threadIdx.x * 4; e < e1; e += 1024) {
    if (e + 4 <= e1) {
      int4 s4 = *(const int4*)(src + e);
      int4 d4 = *(const int4*)(dst + e);
      if (d4.x >= lo && d4.x < hi) atomicAdd(&cntd[d4.x - lo], 1);
      if (d4.y >= lo && d4.y < hi) atomicAdd(&cntd[d4.y - lo], 1);
      if (d4.z >= lo && d4.z < hi) atomicAdd(&cntd[d4.z - lo], 1);
      if (d4.w >= lo && d4.w < hi) atomicAdd(&cntd[d4.w - lo], 1);
      if (s4.x >= lo && s4.x < hi) atomicAdd(&cnts[s4.x - lo], 1);
      if (s4.y >= lo && s4.y < hi) atomicAdd(&cnts[s4.y - lo], 1);
      if (s4.z >= lo && s4.z < hi) atomicAdd(&cnts[s4.z - lo], 1);
      if (s4.w >= lo && s4.w < hi) atomicAdd(&cnts[s4.w - lo], 1);
    } else {
      for (int k = e; k < e1; ++k) {
        int s = src[k], d = dst[k];
        if (d >= lo && d < hi) atomicAdd(&cntd[d - lo], 1);
        if (s >= lo && s < hi) atomicAdd(&cnts[s - lo], 1);
      }
    }
  }
  __syncthreads();
  for (int i = threadIdx.x; i < range; i += 256) {
    Hd[(size_t)c * N + lo + i] = cntd[i];
    Hs[(size_t)c * N + lo + i] = cnts[i];
  }
}

__global__ __launch_bounds__(256) void degsum_kernel(
    const int* __restrict__ Hd, const int* __restrict__ Hs,
    int* __restrict__ deg_d, int* __restrict__ deg_s, int N) {
  int n = blockIdx.x * 256 + threadIdx.x;
  if (n >= N) return;
  int sd = 0, ss = 0;
#pragma unroll
  for (int c = 0; c < NCHK; ++c) {
    sd += Hd[(size_t)c * N + n];
    ss += Hs[(size_t)c * N + n];
  }
  deg_d[n] = sd;
  deg_s[n] = ss;
}

__global__ __launch_bounds__(256) void scan_partial(
    const int* __restrict__ deg_d, const int* __restrict__ deg_s,
    int* __restrict__ bsum, int n, int nb) {
  const int* deg = (blockIdx.y == 0) ? deg_d : deg_s;
  int tid = threadIdx.x;
  int base = blockIdx.x * SCAN_ELEMS;
  int s = 0;
#pragma unroll
  for (int j = 0; j < 8; ++j) {
    int i = base + j * 256 + tid;
    if (i < n) s += deg[i];
  }
#pragma unroll
  for (int off = 1; off < 64; off <<= 1) s += __shfl_xor(s, off);
  __shared__ int ws[4];
  if ((tid & 63) == 0) ws[tid >> 6] = s;
  __syncthreads();
  if (tid == 0) bsum[blockIdx.y * nb + blockIdx.x] = ws[0] + ws[1] + ws[2] + ws[3];
}

__global__ __launch_bounds__(256) void scan_bsum(int* __restrict__ bsum, int nb) {
  __shared__ int sh[256];
  int tid = threadIdx.x;
  for (int h = 0; h < 2; ++h) {
    int v = (tid < nb) ? bsum[h * nb + tid] : 0;
    sh[tid] = v;
    __syncthreads();
    for (int off = 1; off < 256; off <<= 1) {
      int t = (tid >= off) ? sh[tid - off] : 0;
      __syncthreads();
      sh[tid] += t;
      __syncthreads();
    }
    if (tid < nb) bsum[h * nb + tid] = sh[tid] - v;  // exclusive
    __syncthreads();
  }
}

__global__ __launch_bounds__(256) void scan_final(
    const int* __restrict__ deg_d, const int* __restrict__ deg_s,
    const int* __restrict__ bsum,
    int* __restrict__ row_d, int* __restrict__ row_s, int n, int nb) {
  const int* deg = (blockIdx.y == 0) ? deg_d : deg_s;
  int* row = (blockIdx.y == 0) ? row_d : row_s;
  int tid = threadIdx.x;
  int lane = tid & 63;
  int e0 = blockIdx.x * SCAN_ELEMS + tid * 8;
  int v[8];
  int s = 0;
#pragma unroll
  for (int j = 0; j < 8; ++j) {
    int i = e0 + j;
    v[j] = (i < n) ? deg[i] : 0;
    s += v[j];
  }
  int incl = s;
#pragma unroll
  for (int off = 1; off < 64; off <<= 1) {
    int t = __shfl_up(incl, off);
    if (lane >= off) incl += t;
  }
  __shared__ int wsum[4];
  if (lane == 63) wsum[tid >> 6] = incl;
  __syncthreads();
  int woff = 0;
  int w = tid >> 6;
  for (int k = 0; k < 4; ++k)
    if (k < w) woff += wsum[k];
  int run = incl - s + woff + bsum[blockIdx.y * nb + blockIdx.x];
#pragma unroll
  for (int j = 0; j < 8; ++j) {
    int i = e0 + j;
    if (i <= n) row[i] = run;
    run += v[j];
  }
}

__global__ __launch_bounds__(256) void cursor_kernel(
    int* __restrict__ Hd, int* __restrict__ Hs,
    const int* __restrict__ row_d, const int* __restrict__ row_s, int N) {
  int n = blockIdx.x * 256 + threadIdx.x;
  if (n >= N) return;
  int rd = row_d[n], rs = row_s[n];
#pragma unroll
  for (int c = 0; c < NCHK; ++c) {
    int t = Hd[(size_t)c * N + n]; Hd[(size_t)c * N + n] = rd; rd += t;
    t = Hs[(size_t)c * N + n];     Hs[(size_t)c * N + n] = rs; rs += t;
  }
}

__global__ __launch_bounds__(256) void scatter_kernel(
    const int* __restrict__ src, const int* __restrict__ dst,
    const int* __restrict__ Hd, const int* __restrict__ Hs,
    int* __restrict__ col_d, int* __restrict__ col_s, int E, int N, int chunk) {
  int c = blockIdx.x, g = blockIdx.y;
  int lo = (int)((long long)N * g / NGRP);
  int hi = (int)((long long)N * (g + 1) / NGRP);
  int range = hi - lo;
  __shared__ int curd[RMAX];
  __shared__ int curs[RMAX];
  for (int i = threadIdx.x; i < range; i += 256) {
    curd[i] = Hd[(size_t)c * N + lo + i];
    curs[i] = Hs[(size_t)c * N + lo + i];
  }
  __syncthreads();
  int e0 = c * chunk, e1 = min(E, e0 + chunk);
  for (int e = e0 + (int)threadIdx.x * 4; e < e1; e += 1024) {
    if (e + 4 <= e1) {
      int4 s4 = *(const int4*)(src + e);
      int4 d4 = *(const int4*)(dst + e);
      if (d4.x >= lo && d4.x < hi) { int p = atomicAdd(&curd[d4.x - lo], 1); col_d[p] = s4.x; }
      if (d4.y >= lo && d4.y < hi) { int p = atomicAdd(&curd[d4.y - lo], 1); col_d[p] = s4.y; }
      if (d4.z >= lo && d4.z < hi) { int p = atomicAdd(&curd[d4.z - lo], 1); col_d[p] = s4.z; }
      if (d4.w >= lo && d4.w < hi) { int p = atomicAdd(&curd[d4.w - lo], 1); col_d[p] = s4.w; }
      if (s4.x >= lo && s4.x < hi) { int p = atomicAdd(&curs[s4.x - lo], 1); col_s[p] = d4.x; }
      if (s4.y >= lo && s4.y < hi) { int p = atomicAdd(&curs[s4.y - lo], 1); col_s[p] = d4.y; }
      if (s4.z >= lo && s4.z < hi) { int p = atomicAdd(&curs[s4.z - lo], 1); col_s[p] = d4.z; }
      if (s4.w >= lo && s4.w < hi) { int p = atomicAdd(&curs[s4.w - lo], 1); col_s[p] = d4.w; }
    } else {
      for (int k = e; k < e1; ++k) {
        int s = src[k], d = dst[k];
        if (d >= lo && d < hi) { int p = atomicAdd(&curd[d - lo], 1); col_d[p] = s; }
        if (s >= lo && s < hi) { int p = atomicAdd(&curs[s - lo], 1); col_s[p] = d; }
      }
    }
  }
}

// ---------------- fused layer: gather-mean (both dirs) -> LDS -> combine ----------------
// phase 1: wave w gathers nodes [n0+16w, n0+16w+16): lane=feature, mean into
//          G1t/G2t LDS tiles; h row staged into Ht.
// phase 2: lane=node over the 64-row tile; wave w computes outputs 16w..16w+15
//          with k-major weights, 1-deep register double-buffer.

__device__ __forceinline__ float gather_mean(
    const float* __restrict__ h, const int* __restrict__ row,
    const int* __restrict__ col, int node, int lane) {
  int s0 = row[node], s1 = row[node + 1];
  float a0 = 0.f, a1 = 0.f, a2 = 0.f, a3 = 0.f;
  int p = s0;
  for (; p + 8 <= s1; p += 8) {
    int n0 = col[p], n1 = col[p + 1], n2 = col[p + 2], n3 = col[p + 3];
    int n4 = col[p + 4], n5 = col[p + 5], n6 = col[p + 6], n7 = col[p + 7];
    a0 += h[(size_t)n0 * NDIM + lane];
    a1 += h[(size_t)n1 * NDIM + lane];
    a2 += h[(size_t)n2 * NDIM + lane];
    a3 += h[(size_t)n3 * NDIM + lane];
    a0 += h[(size_t)n4 * NDIM + lane];
    a1 += h[(size_t)n5 * NDIM + lane];
    a2 += h[(size_t)n6 * NDIM + lane];
    a3 += h[(size_t)n7 * NDIM + lane];
  }
  for (; p + 4 <= s1; p += 4) {
    int n0 = col[p], n1 = col[p + 1], n2 = col[p + 2], n3 = col[p + 3];
    a0 += h[(size_t)n0 * NDIM + lane];
    a1 += h[(size_t)n1 * NDIM + lane];
    a2 += h[(size_t)n2 * NDIM + lane];
    a3 += h[(size_t)n3 * NDIM + lane];
  }
  for (; p < s1; ++p) a0 += h[(size_t)col[p] * NDIM + lane];
  float sum = (a0 + a1) + (a2 + a3);
  int cnt = s1 - s0;
  float inv = cnt > 0 ? 1.f / (float)cnt : 0.f;
  return sum * inv;
}

__global__ __launch_bounds__(256, 3) void layer_kernel(
    const float* __restrict__ h,
    const int* __restrict__ row_d, const int* __restrict__ col_d,
    const int* __restrict__ row_s, const int* __restrict__ col_s,
    const float* __restrict__ wrT, const float* __restrict__ w1T,
    const float* __restrict__ w2T, const float* __restrict__ bias,
    float* __restrict__ hout, int N) {
  __shared__ float Ht[64][65];
  __shared__ float G1t[64][65];
  __shared__ float G2t[64][65];
  int tid = threadIdx.x;
  int w = __builtin_amdgcn_readfirstlane(tid >> 6);
  int lane = tid & 63;
  int n0 = blockIdx.x * 64;
  // ---- phase 1: gather 16 nodes per wave ----
  for (int i = 0; i < 16; ++i) {
    int r = w * 16 + i;
    int node = n0 + r;
    int nc = node < N ? node : N - 1;
    Ht[r][lane] = h[(size_t)nc * NDIM + lane];
    G1t[r][lane] = gather_mean(h, row_d, col_d, nc, lane);
    G2t[r][lane] = gather_mean(h, row_s, col_s, nc, lane);
  }
  __syncthreads();
  // ---- phase 2: combine ----
  int ob = w * 16;
  float acc[16];
#pragma unroll
  for (int o = 0; o < 16; ++o) acc[o] = bias[ob + o];
  float4 nA[4], nB[4], nC[4];
  float nh, n1v, n2v;
  {
    const float4* pa = (const float4*)(wrT + ob);
    const float4* pb = (const float4*)(w1T + ob);
    const float4* pc = (const float4*)(w2T + ob);
#pragma unroll
    for (int j = 0; j < 4; ++j) { nA[j] = pa[j]; nB[j] = pb[j]; nC[j] = pc[j]; }
    nh = Ht[lane][0]; n1v = G1t[lane][0]; n2v = G2t[lane][0];
  }
  for (int k = 0; k < 64; ++k) {
    float4 A[4], B[4], C[4];
    float hv = nh, v1 = n1v, v2 = n2v;
#pragma unroll
    for (int j = 0; j < 4; ++j) { A[j] = nA[j]; B[j] = nB[j]; C[j] = nC[j]; }
    if (k < 63) {
      int k1 = k + 1;
      const float4* pa = (const float4*)(wrT + k1 * 64 + ob);
      const float4* pb = (const float4*)(w1T + k1 * 64 + ob);
      const float4* pc = (const float4*)(w2T + k1 * 64 + ob);
#pragma unroll
      for (int j = 0; j < 4; ++j) { nA[j] = pa[j]; nB[j] = pb[j]; nC[j] = pc[j]; }
      nh = Ht[lane][k1]; n1v = G1t[lane][k1]; n2v = G2t[lane][k1];
    }
#pragma unroll
    for (int j = 0; j < 4; ++j) {
      acc[4*j+0] += hv * A[j].x + v1 * B[j].x + v2 * C[j].x;
      acc[4*j+1] += hv * A[j].y + v1 * B[j].y + v2 * C[j].y;
      acc[4*j+2] += hv * A[j].z + v1 * B[j].z + v2 * C[j].z;
      acc[4*j+3] += hv * A[j].w + v1 * B[j].w + v2 * C[j].w;
    }
  }
  int node = n0 + lane;
  if (node < N) {
    float4* op = (float4*)(hout + (size_t)node * NDIM + ob);
#pragma unroll
    for (int j = 0; j < 4; ++j) {
      float4 v;
      v.x = fmaxf(acc[4*j+0], 0.f);
      v.y = fmaxf(acc[4*j+1], 0.f);
      v.z = fmaxf(acc[4*j+2], 0.f);
      v.w = fmaxf(acc[4*j+3], 0.f);
      op[j] = v;
    }
  }
}

// ---------------- final: 64-node LDS tile (4 input bufs), lane=node ----------------

__global__ __launch_bounds__(256, 2) void final_kernel(
    const float* __restrict__ x, const float* __restrict__ h1,
    const float* __restrict__ h2, const float* __restrict__ h3,
    const float* __restrict__ fwT, const float* __restrict__ fb,
    float* __restrict__ outp, int N) {
  __shared__ float Ft[4][64][65];
  int tid = threadIdx.x;
  int n0 = blockIdx.x * 64;
  int r = tid >> 2;
  bool ok = (n0 + r) < N;
  const float* bufs[4] = {x, h1, h2, h3};
#pragma unroll
  for (int b = 0; b < 4; ++b) {
    const float4* ip = (const float4*)(bufs[b] + (size_t)(n0 + r) * NDIM);
#pragma unroll
    for (int i = 0; i < 4; ++i) {
      int q = (tid & 3) + i * 4;
      float4 v = ok ? ip[q] : float4{0.f, 0.f, 0.f, 0.f};
      Ft[b][r][q*4+0]=v.x; Ft[b][r][q*4+1]=v.y; Ft[b][r][q*4+2]=v.z; Ft[b][r][q*4+3]=v.w;
    }
  }
  __syncthreads();
  int w = __builtin_amdgcn_readfirstlane(tid >> 6);
  int lane = tid & 63;
  int ob = w * 16;
  float acc[16];
#pragma unroll
  for (int o = 0; o < 16; ++o) acc[o] = fb[ob + o];
  float4 nW[4];
  float nv;
  {
    const float4* wp = (const float4*)(fwT + ob);
#pragma unroll
    for (int j = 0; j < 4; ++j) nW[j] = wp[j];
    nv = Ft[0][lane][0];
  }
  for (int k = 0; k < 256; ++k) {
    float4 W[4];
    float v = nv;
#pragma unroll
    for (int j = 0; j < 4; ++j) W[j] = nW[j];
    if (k < 255) {
      int k1 = k + 1;
      const float4* wp = (const float4*)(fwT + k1 * 64 + ob);
#pragma unroll
      for (int j = 0; j < 4; ++j) nW[j] = wp[j];
      nv = Ft[k1 >> 6][lane][k1 & 63];
    }
#pragma unroll
    for (int j = 0; j < 4; ++j) {
      acc[4*j+0] += v * W[j].x;
      acc[4*j+1] += v * W[j].y;
      acc[4*j+2] += v * W[j].z;
      acc[4*j+3] += v * W[j].w;
    }
  }
  int node = n0 + lane;
  if (node < N) {
    float4* op = (float4*)(outp + (size_t)node * NDIM + ob);
#pragma unroll
    for (int j = 0; j < 4; ++j) {
      float4 v;
      v.x = acc[4*j+0]; v.y = acc[4*j+1]; v.z = acc[4*j+2]; v.w = acc[4*j+3];
      op[j] = v;
    }
  }
}

// ---------------- launch ----------------

extern "C" void kernel_launch(void* const* d_in, const int* in_sizes, int n_in,
                              void* d_out, int out_size, void* d_ws, size_t ws_size,
                              hipStream_t stream) {
  const float* x     = (const float*)d_in[0];
  const int*   ei    = (const int*)d_in[1];
  const float* lin1  = (const float*)d_in[2];
  const float* lin2  = (const float*)d_in[3];
  const float* rootw = (const float*)d_in[4];
  const float* rootb = (const float*)d_in[5];
  const float* fw    = (const float*)d_in[6];
  const float* fb    = (const float*)d_in[7];
  float* out = (float*)d_out;

  int N = in_sizes[0] / NDIM;
  int E = in_sizes[1] / 2;
  const int* src = ei;
  const int* dst = ei + E;

  int* ip = (int*)d_ws;
  int* Hd    = ip; ip += (size_t)NCHK * N;
  int* Hs    = ip; ip += (size_t)NCHK * N;
  int* deg_d = ip; ip += N;
  int* deg_s = ip; ip += N;
  int* row_d = ip; ip += N + 1;
  int* row_s = ip; ip += N + 1;
  int* bsum  = ip; ip += 256;
  int* col_d = ip; ip += E;
  int* col_s = ip; ip += E;
  uintptr_t fbase = (((uintptr_t)ip) + 255) & ~(uintptr_t)255;
  float* fwT = (float*)fbase;
  float* wrT = fwT + 16384;
  float* w1T = wrT + 12288;
  float* w2T = w1T + 12288;
  float* h1  = w2T + 12288;
  float* h2 = h1 + (size_t)N * NDIM;
  float* h3 = h2 + (size_t)N * NDIM;

  int chunk = (E + NCHK - 1) / NCHK;
  int nb = (N + SCAN_ELEMS - 1) / SCAN_ELEMS;
  int nblk = (N + 255) / 256;

  transpose_kernel<<<112, 256, 0, stream>>>(fw, rootw, lin1, lin2, fwT, wrT, w1T, w2T);
  hist_kernel<<<dim3(NCHK, NGRP), 256, 0, stream>>>(src, dst, Hd, Hs, E, N, chunk);
  degsum_kernel<<<nblk, 256, 0, stream>>>(Hd, Hs, deg_d, deg_s, N);
  scan_partial<<<dim3(nb, 2), 256, 0, stream>>>(deg_d, deg_s, bsum, N, nb);
  scan_bsum<<<1, 256, 0, stream>>>(bsum, nb);
  scan_final<<<dim3(nb, 2), 256, 0, stream>>>(deg_d, deg_s, bsum, row_d, row_s, N, nb);
  cursor_kernel<<<nblk, 256, 0, stream>>>(Hd, Hs, row_d, row_s, N);
  scatter_kernel<<<dim3(NCHK, NGRP), 256, 0, stream>>>(src, dst, Hd, Hs,
                                                       col_d, col_s, E, N, chunk);

  int tgrid = (N + 63) / 64;
  const float* hbufs[4] = {x, h1, h2, h3};
  for (int l = 0; l < 3; ++l) {
    layer_kernel<<<tgrid, 256, 0, stream>>>(hbufs[l], row_d, col_d, row_s, col_s,
                                            wrT + (size_t)l * 4096,
                                            w1T + (size_t)l * 4096,
                                            w2T + (size_t)l * 4096,
                                            rootb + (size_t)l * 64,
                                            (float*)hbufs[l + 1], N);
  }
  final_kernel<<<tgrid, 256, 0, stream>>>(x, h1, h2, h3, fwT, fb, out, N);
}

// Round 8
// 464.040 us; speedup vs baseline: 1.2942x; 1.2942x over previous
//
#include <hip/hip_runtime.h>
#include <stdint.h>

#define NDIM 64
#define SCAN_ELEMS 2048   // elements per scan block (256 thr x 8)
#define NCHK 16           // edge chunks
#define NGRP 8            // node-range groups
#define RMAX 6272         // max nodes per group (ceil(50000/8)=6250)

typedef unsigned int uint;
typedef unsigned short ushort;

// round-to-nearest-even fp32 -> bf16 (pair packed into a uint)
__device__ __forceinline__ uint f2bf2(float a, float b) {
  uint ua = __float_as_uint(a);
  uint ub = __float_as_uint(b);
  ua += 0x7fffu + ((ua >> 16) & 1u);
  ub += 0x7fffu + ((ub >> 16) & 1u);
  return (ua >> 16) | (ub & 0xffff0000u);
}

// ---------------- weight transpose (k-major) ----------------
__global__ __launch_bounds__(256) void transpose_kernel(
    const float* __restrict__ fw, const float* __restrict__ rootw,
    const float* __restrict__ lin1, const float* __restrict__ lin2,
    float* __restrict__ fwT, float* __restrict__ wrT,
    float* __restrict__ w1T, float* __restrict__ w2T) {
  int e = blockIdx.x * 256 + threadIdx.x;
  if (e < 16384) {
    int o = e >> 8, k = e & 255;
    fwT[k * 64 + o] = fw[e];
  }
  int e2 = e - 16384;
  if (e2 >= 0 && e2 < 12288) {
    int l = e2 >> 12, r = e2 & 4095;
    int o = r >> 6, k = r & 63;
    size_t t = (size_t)l * 4096 + k * 64 + o;
    wrT[t] = rootw[e2];
    w1T[t] = lin1[e2];
    w2T[t] = lin2[e2];
  }
}

// ---------------- x -> bf16 table ----------------
__global__ __launch_bounds__(256) void convx_kernel(
    const float* __restrict__ x, uint* __restrict__ xb, int n4) {
  int e = blockIdx.x * 256 + threadIdx.x;
  if (e >= n4) return;
  float4 v = ((const float4*)x)[e];
  uint2 o;
  o.x = f2bf2(v.x, v.y);
  o.y = f2bf2(v.z, v.w);
  ((uint2*)xb)[e] = o;
}

// ---------------- CSR build: atomic-free chunked counting sort ----------------
__global__ __launch_bounds__(256) void hist_kernel(
    const int* __restrict__ src, const int* __restrict__ dst,
    int* __restrict__ Hd, int* __restrict__ Hs, int E, int N, int chunk) {
  int c = blockIdx.x, g = blockIdx.y;
  int lo = (int)((long long)N * g / NGRP);
  int hi = (int)((long long)N * (g + 1) / NGRP);
  int range = hi - lo;
  __shared__ int cntd[RMAX];
  __shared__ int cnts[RMAX];
  for (int i = threadIdx.x; i < range; i += 256) { cntd[i] = 0; cnts[i] = 0; }
  __syncthreads();
  int e0 = c * chunk, e1 = min(E, e0 + chunk);
  for (int e = e0 + (int)threadIdx.x * 4; e < e1; e += 1024) {
    if (e + 4 <= e1) {
      int4 s4 = *(const int4*)(src + e);
      int4 d4 = *(const int4*)(dst + e);
      if (d4.x >= lo && d4.x < hi) atomicAdd(&cntd[d4.x - lo], 1);
      if (d4.y >= lo && d4.y < hi) atomicAdd(&cntd[d4.y - lo], 1);
      if (d4.z >= lo && d4.z < hi) atomicAdd(&cntd[d4.z - lo], 1);
      if (d4.w >= lo && d4.w < hi) atomicAdd(&cntd[d4.w - lo], 1);
      if (s4.x >= lo && s4.x < hi) atomicAdd(&cnts[s4.x - lo], 1);
      if (s4.y >= lo && s4.y < hi) atomicAdd(&cnts[s4.y - lo], 1);
      if (s4.z >= lo && s4.z < hi) atomicAdd(&cnts[s4.z - lo], 1);
      if (s4.w >= lo && s4.w < hi) atomicAdd(&cnts[s4.w - lo], 1);
    } else {
      for (int k = e; k < e1; ++k) {
        int s = src[k], d = dst[k];
        if (d >= lo && d < hi) atomicAdd(&cntd[d - lo], 1);
        if (s >= lo && s < hi) atomicAdd(&cnts[s - lo], 1);
      }
    }
  }
  __syncthreads();
  for (int i = threadIdx.x; i < range; i += 256) {
    Hd[(size_t)c * N + lo + i] = cntd[i];
    Hs[(size_t)c * N + lo + i] = cnts[i];
  }
}

__global__ __launch_bounds__(256) void degsum_kernel(
    const int* __restrict__ Hd, const int* __restrict__ Hs,
    int* __restrict__ deg_d, int* __restrict__ deg_s, int N) {
  int n = blockIdx.x * 256 + threadIdx.x;
  if (n >= N) return;
  int sd = 0, ss = 0;
#pragma unroll
  for (int c = 0; c < NCHK; ++c) {
    sd += Hd[(size_t)c * N + n];
    ss += Hs[(size_t)c * N + n];
  }
  deg_d[n] = sd;
  deg_s[n] = ss;
}

__global__ __launch_bounds__(256) void scan_partial(
    const int* __restrict__ deg_d, const int* __restrict__ deg_s,
    int* __restrict__ bsum, int n, int nb) {
  const int* deg = (blockIdx.y == 0) ? deg_d : deg_s;
  int tid = threadIdx.x;
  int base = blockIdx.x * SCAN_ELEMS;
  int s = 0;
#pragma unroll
  for (int j = 0; j < 8; ++j) {
    int i = base + j * 256 + tid;
    if (i < n) s += deg[i];
  }
#pragma unroll
  for (int off = 1; off < 64; off <<= 1) s += __shfl_xor(s, off);
  __shared__ int ws[4];
  if ((tid & 63) == 0) ws[tid >> 6] = s;
  __syncthreads();
  if (tid == 0) bsum[blockIdx.y * nb + blockIdx.x] = ws[0] + ws[1] + ws[2] + ws[3];
}

__global__ __launch_bounds__(256) void scan_bsum(int* __restrict__ bsum, int nb) {
  __shared__ int sh[256];
  int tid = threadIdx.x;
  for (int h = 0; h < 2; ++h) {
    int v = (tid < nb) ? bsum[h * nb + tid] : 0;
    sh[tid] = v;
    __syncthreads();
    for (int off = 1; off < 256; off <<= 1) {
      int t = (tid >= off) ? sh[tid - off] : 0;
      __syncthreads();
      sh[tid] += t;
      __syncthreads();
    }
    if (tid < nb) bsum[h * nb + tid] = sh[tid] - v;  // exclusive
    __syncthreads();
  }
}

__global__ __launch_bounds__(256) void scan_final(
    const int* __restrict__ deg_d, const int* __restrict__ deg_s,
    const int* __restrict__ bsum,
    int* __restrict__ row_d, int* __restrict__ row_s, int n, int nb) {
  const int* deg = (blockIdx.y == 0) ? deg_d : deg_s;
  int* row = (blockIdx.y == 0) ? row_d : row_s;
  int tid = threadIdx.x;
  int lane = tid & 63;
  int e0 = blockIdx.x * SCAN_ELEMS + tid * 8;
  int v[8];
  int s = 0;
#pragma unroll
  for (int j = 0; j < 8; ++j) {
    int i = e0 + j;
    v[j] = (i < n) ? deg[i] : 0;
    s += v[j];
  }
  int incl = s;
#pragma unroll
  for (int off = 1; off < 64; off <<= 1) {
    int t = __shfl_up(incl, off);
    if (lane >= off) incl += t;
  }
  __shared__ int wsum[4];
  if (lane == 63) wsum[tid >> 6] = incl;
  __syncthreads();
  int woff = 0;
  int w = tid >> 6;
  for (int k = 0; k < 4; ++k)
    if (k < w) woff += wsum[k];
  int run = incl - s + woff + bsum[blockIdx.y * nb + blockIdx.x];
#pragma unroll
  for (int j = 0; j < 8; ++j) {
    int i = e0 + j;
    if (i <= n) row[i] = run;
    run += v[j];
  }
}

__global__ __launch_bounds__(256) void cursor_kernel(
    int* __restrict__ Hd, int* __restrict__ Hs,
    const int* __restrict__ row_d, const int* __restrict__ row_s, int N) {
  int n = blockIdx.x * 256 + threadIdx.x;
  if (n >= N) return;
  int rd = row_d[n], rs = row_s[n];
#pragma unroll
  for (int c = 0; c < NCHK; ++c) {
    int t = Hd[(size_t)c * N + n]; Hd[(size_t)c * N + n] = rd; rd += t;
    t = Hs[(size_t)c * N + n];     Hs[(size_t)c * N + n] = rs; rs += t;
  }
}

__global__ __launch_bounds__(256) void scatter_kernel(
    const int* __restrict__ src, const int* __restrict__ dst,
    const int* __restrict__ Hd, const int* __restrict__ Hs,
    int* __restrict__ col_d, int* __restrict__ col_s, int E, int N, int chunk) {
  int c = blockIdx.x, g = blockIdx.y;
  int lo = (int)((long long)N * g / NGRP);
  int hi = (int)((long long)N * (g + 1) / NGRP);
  int range = hi - lo;
  __shared__ int curd[RMAX];
  __shared__ int curs[RMAX];
  for (int i = threadIdx.x; i < range; i += 256) {
    curd[i] = Hd[(size_t)c * N + lo + i];
    curs[i] = Hs[(size_t)c * N + lo + i];
  }
  __syncthreads();
  int e0 = c * chunk, e1 = min(E, e0 + chunk);
  for (int e = e0 + (int)threadIdx.x * 4; e < e1; e += 1024) {
    if (e + 4 <= e1) {
      int4 s4 = *(const int4*)(src + e);
      int4 d4 = *(const int4*)(dst + e);
      if (d4.x >= lo && d4.x < hi) { int p = atomicAdd(&curd[d4.x - lo], 1); col_d[p] = s4.x; }
      if (d4.y >= lo && d4.y < hi) { int p = atomicAdd(&curd[d4.y - lo], 1); col_d[p] = s4.y; }
      if (d4.z >= lo && d4.z < hi) { int p = atomicAdd(&curd[d4.z - lo], 1); col_d[p] = s4.z; }
      if (d4.w >= lo && d4.w < hi) { int p = atomicAdd(&curd[d4.w - lo], 1); col_d[p] = s4.w; }
      if (s4.x >= lo && s4.x < hi) { int p = atomicAdd(&curs[s4.x - lo], 1); col_s[p] = d4.x; }
      if (s4.y >= lo && s4.y < hi) { int p = atomicAdd(&curs[s4.y - lo], 1); col_s[p] = d4.y; }
      if (s4.z >= lo && s4.z < hi) { int p = atomicAdd(&curs[s4.z - lo], 1); col_s[p] = d4.z; }
      if (s4.w >= lo && s4.w < hi) { int p = atomicAdd(&curs[s4.w - lo], 1); col_s[p] = d4.w; }
    } else {
      for (int k = e; k < e1; ++k) {
        int s = src[k], d = dst[k];
        if (d >= lo && d < hi) { int p = atomicAdd(&curd[d - lo], 1); col_d[p] = s; }
        if (s >= lo && s < hi) { int p = atomicAdd(&curs[s - lo], 1); col_s[p] = d; }
      }
    }
  }
}

// ---------------- aggregation (bf16 table): wave per node ----------------
// Lane-halves process 2 neighbors concurrently: half = lane>>5 picks the
// neighbor parity, fl = lane&31 the feature pair (bf16x2 = 4B per lane,
// 32 lanes = one 128B row). Merge halves with shfl_xor(.,32) at the end.

#define GLOAD(ACCX, ACCY, NODE) {                                            \
    uint u_ = *(const uint*)(hB + (size_t)(NODE) * 64 + fl * 2);             \
    ACCX += __uint_as_float(u_ << 16);                                       \
    ACCY += __uint_as_float(u_ & 0xffff0000u);                               \
  }

__global__ __launch_bounds__(256) void agg2b_kernel(
    const ushort* __restrict__ hB,
    const int* __restrict__ row_d, const int* __restrict__ col_d, float* __restrict__ g1,
    const int* __restrict__ row_s, const int* __restrict__ col_s, float* __restrict__ g2,
    int N) {
  const int* row = (blockIdx.y == 0) ? row_d : row_s;
  const int* col = (blockIdx.y == 0) ? col_d : col_s;
  float* outp = (blockIdx.y == 0) ? g1 : g2;
  int wid = blockIdx.x * 4 + (threadIdx.x >> 6);
  int lane = threadIdx.x & 63;
  int half = lane >> 5;
  int fl = lane & 31;
  if (wid >= N) return;
  int s0 = row[wid], s1 = row[wid + 1];
  float ax0 = 0.f, ay0 = 0.f, ax1 = 0.f, ay1 = 0.f;
  float ax2 = 0.f, ay2 = 0.f, ax3 = 0.f, ay3 = 0.f;
  int p = s0;
  for (; p + 16 <= s1; p += 16) {
    int n0 = col[p + 0 + half],  n1 = col[p + 2 + half];
    int n2 = col[p + 4 + half],  n3 = col[p + 6 + half];
    int n4 = col[p + 8 + half],  n5 = col[p + 10 + half];
    int n6 = col[p + 12 + half], n7 = col[p + 14 + half];
    GLOAD(ax0, ay0, n0); GLOAD(ax1, ay1, n1);
    GLOAD(ax2, ay2, n2); GLOAD(ax3, ay3, n3);
    GLOAD(ax0, ay0, n4); GLOAD(ax1, ay1, n5);
    GLOAD(ax2, ay2, n6); GLOAD(ax3, ay3, n7);
  }
  for (; p + 2 <= s1; p += 2) {
    int n = col[p + half];
    GLOAD(ax0, ay0, n);
  }
  if (p < s1 && half == 0) {
    int n = col[p];
    GLOAD(ax1, ay1, n);
  }
  float sx = (ax0 + ax1) + (ax2 + ax3);
  float sy = (ay0 + ay1) + (ay2 + ay3);
  sx += __shfl_xor(sx, 32);
  sy += __shfl_xor(sy, 32);
  int cnt = s1 - s0;
  float inv = cnt > 0 ? 1.f / (float)cnt : 0.f;
  if (half == 0) {
    float2 v; v.x = sx * inv; v.y = sy * inv;
    ((float2*)(outp + (size_t)wid * NDIM))[fl] = v;
  }
}

// ---------------- combine: 64-node LDS tile, lane=node, wave=16 outputs ----------------
// Also emits the bf16 copy of hout for the next layer's gather (hbout != null).

__global__ __launch_bounds__(256, 3) void combine_kernel(
    const float* __restrict__ h, const float* __restrict__ g1,
    const float* __restrict__ g2, const float* __restrict__ wrT,
    const float* __restrict__ w1T, const float* __restrict__ w2T,
    const float* __restrict__ bias, float* __restrict__ hout,
    ushort* __restrict__ hbout, int N) {
  __shared__ float Ht[64][65];
  __shared__ float G1t[64][65];
  __shared__ float G2t[64][65];
  int tid = threadIdx.x;
  int n0 = blockIdx.x * 64;
  int r = tid >> 2;
  bool ok = (n0 + r) < N;
  const float4* hp = (const float4*)(h  + (size_t)(n0 + r) * NDIM);
  const float4* q1 = (const float4*)(g1 + (size_t)(n0 + r) * NDIM);
  const float4* q2 = (const float4*)(g2 + (size_t)(n0 + r) * NDIM);
#pragma unroll
  for (int i = 0; i < 4; ++i) {
    int q = (tid & 3) + i * 4;
    float4 a = ok ? hp[q] : float4{0.f, 0.f, 0.f, 0.f};
    float4 b = ok ? q1[q] : float4{0.f, 0.f, 0.f, 0.f};
    float4 c = ok ? q2[q] : float4{0.f, 0.f, 0.f, 0.f};
    Ht[r][q*4+0]=a.x;  Ht[r][q*4+1]=a.y;  Ht[r][q*4+2]=a.z;  Ht[r][q*4+3]=a.w;
    G1t[r][q*4+0]=b.x; G1t[r][q*4+1]=b.y; G1t[r][q*4+2]=b.z; G1t[r][q*4+3]=b.w;
    G2t[r][q*4+0]=c.x; G2t[r][q*4+1]=c.y; G2t[r][q*4+2]=c.z; G2t[r][q*4+3]=c.w;
  }
  __syncthreads();
  int w = __builtin_amdgcn_readfirstlane(tid >> 6);
  int lane = tid & 63;
  int ob = w * 16;
  float acc[16];
#pragma unroll
  for (int o = 0; o < 16; ++o) acc[o] = bias[ob + o];
  float4 nA[4], nB[4], nC[4];
  float nh, n1v, n2v;
  {
    const float4* pa = (const float4*)(wrT + ob);
    const float4* pb = (const float4*)(w1T + ob);
    const float4* pc = (const float4*)(w2T + ob);
#pragma unroll
    for (int j = 0; j < 4; ++j) { nA[j] = pa[j]; nB[j] = pb[j]; nC[j] = pc[j]; }
    nh = Ht[lane][0]; n1v = G1t[lane][0]; n2v = G2t[lane][0];
  }
  for (int k = 0; k < 64; ++k) {
    float4 A[4], B[4], C[4];
    float hv = nh, v1 = n1v, v2 = n2v;
#pragma unroll
    for (int j = 0; j < 4; ++j) { A[j] = nA[j]; B[j] = nB[j]; C[j] = nC[j]; }
    if (k < 63) {
      int k1 = k + 1;
      const float4* pa = (const float4*)(wrT + k1 * 64 + ob);
      const float4* pb = (const float4*)(w1T + k1 * 64 + ob);
      const float4* pc = (const float4*)(w2T + k1 * 64 + ob);
#pragma unroll
      for (int j = 0; j < 4; ++j) { nA[j] = pa[j]; nB[j] = pb[j]; nC[j] = pc[j]; }
      nh = Ht[lane][k1]; n1v = G1t[lane][k1]; n2v = G2t[lane][k1];
    }
#pragma unroll
    for (int j = 0; j < 4; ++j) {
      acc[4*j+0] += hv * A[j].x + v1 * B[j].x + v2 * C[j].x;
      acc[4*j+1] += hv * A[j].y + v1 * B[j].y + v2 * C[j].y;
      acc[4*j+2] += hv * A[j].z + v1 * B[j].z + v2 * C[j].z;
      acc[4*j+3] += hv * A[j].w + v1 * B[j].w + v2 * C[j].w;
    }
  }
  int node = n0 + lane;
  if (node < N) {
    float rl[16];
#pragma unroll
    for (int o = 0; o < 16; ++o) rl[o] = fmaxf(acc[o], 0.f);
    float4* op = (float4*)(hout + (size_t)node * NDIM + ob);
#pragma unroll
    for (int j = 0; j < 4; ++j) {
      float4 v;
      v.x = rl[4*j+0]; v.y = rl[4*j+1]; v.z = rl[4*j+2]; v.w = rl[4*j+3];
      op[j] = v;
    }
    if (hbout) {
      uint4 u0, u1;
      u0.x = f2bf2(rl[0],  rl[1]);  u0.y = f2bf2(rl[2],  rl[3]);
      u0.z = f2bf2(rl[4],  rl[5]);  u0.w = f2bf2(rl[6],  rl[7]);
      u1.x = f2bf2(rl[8],  rl[9]);  u1.y = f2bf2(rl[10], rl[11]);
      u1.z = f2bf2(rl[12], rl[13]); u1.w = f2bf2(rl[14], rl[15]);
      uint4* bp = (uint4*)(hbout + (size_t)node * NDIM + ob);
      bp[0] = u0; bp[1] = u1;
    }
  }
}

// ---------------- final: 64-node LDS tile (4 input bufs), lane=node ----------------

__global__ __launch_bounds__(256, 2) void final_kernel(
    const float* __restrict__ x, const float* __restrict__ h1,
    const float* __restrict__ h2, const float* __restrict__ h3,
    const float* __restrict__ fwT, const float* __restrict__ fb,
    float* __restrict__ outp, int N) {
  __shared__ float Ft[4][64][65];
  int tid = threadIdx.x;
  int n0 = blockIdx.x * 64;
  int r = tid >> 2;
  bool ok = (n0 + r) < N;
  const float* bufs[4] = {x, h1, h2, h3};
#pragma unroll
  for (int b = 0; b < 4; ++b) {
    const float4* ip = (const float4*)(bufs[b] + (size_t)(n0 + r) * NDIM);
#pragma unroll
    for (int i = 0; i < 4; ++i) {
      int q = (tid & 3) + i * 4;
      float4 v = ok ? ip[q] : float4{0.f, 0.f, 0.f, 0.f};
      Ft[b][r][q*4+0]=v.x; Ft[b][r][q*4+1]=v.y; Ft[b][r][q*4+2]=v.z; Ft[b][r][q*4+3]=v.w;
    }
  }
  __syncthreads();
  int w = __builtin_amdgcn_readfirstlane(tid >> 6);
  int lane = tid & 63;
  int ob = w * 16;
  float acc[16];
#pragma unroll
  for (int o = 0; o < 16; ++o) acc[o] = fb[ob + o];
  float4 nW[4];
  float nv;
  {
    const float4* wp = (const float4*)(fwT + ob);
#pragma unroll
    for (int j = 0; j < 4; ++j) nW[j] = wp[j];
    nv = Ft[0][lane][0];
  }
  for (int k = 0; k < 256; ++k) {
    float4 W[4];
    float v = nv;
#pragma unroll
    for (int j = 0; j < 4; ++j) W[j] = nW[j];
    if (k < 255) {
      int k1 = k + 1;
      const float4* wp = (const float4*)(fwT + k1 * 64 + ob);
#pragma unroll
      for (int j = 0; j < 4; ++j) nW[j] = wp[j];
      nv = Ft[k1 >> 6][lane][k1 & 63];
    }
#pragma unroll
    for (int j = 0; j < 4; ++j) {
      acc[4*j+0] += v * W[j].x;
      acc[4*j+1] += v * W[j].y;
      acc[4*j+2] += v * W[j].z;
      acc[4*j+3] += v * W[j].w;
    }
  }
  int node = n0 + lane;
  if (node < N) {
    float4* op = (float4*)(outp + (size_t)node * NDIM + ob);
#pragma unroll
    for (int j = 0; j < 4; ++j) {
      float4 v;
      v.x = acc[4*j+0]; v.y = acc[4*j+1]; v.z = acc[4*j+2]; v.w = acc[4*j+3];
      op[j] = v;
    }
  }
}

// ---------------- launch ----------------

extern "C" void kernel_launch(void* const* d_in, const int* in_sizes, int n_in,
                              void* d_out, int out_size, void* d_ws, size_t ws_size,
                              hipStream_t stream) {
  const float* x     = (const float*)d_in[0];
  const int*   ei    = (const int*)d_in[1];
  const float* lin1  = (const float*)d_in[2];
  const float* lin2  = (const float*)d_in[3];
  const float* rootw = (const float*)d_in[4];
  const float* rootb = (const float*)d_in[5];
  const float* fw    = (const float*)d_in[6];
  const float* fb    = (const float*)d_in[7];
  float* out = (float*)d_out;

  int N = in_sizes[0] / NDIM;
  int E = in_sizes[1] / 2;
  const int* src = ei;
  const int* dst = ei + E;

  int* ip = (int*)d_ws;
  int* Hd    = ip; ip += (size_t)NCHK * N;
  int* Hs    = ip; ip += (size_t)NCHK * N;
  int* deg_d = ip; ip += N;
  int* deg_s = ip; ip += N;
  int* row_d = ip; ip += N + 1;
  int* row_s = ip; ip += N + 1;
  int* bsum  = ip; ip += 256;
  int* col_d = ip; ip += E;
  int* col_s = ip; ip += E;
  uintptr_t fbase = (((uintptr_t)ip) + 255) & ~(uintptr_t)255;
  float* fwT = (float*)fbase;
  float* wrT = fwT + 16384;
  float* w1T = wrT + 12288;
  float* w2T = w1T + 12288;
  float* h1  = w2T + 12288;
  float* h2 = h1 + (size_t)N * NDIM;
  float* h3 = h2 + (size_t)N * NDIM;
  float* g1 = h3 + (size_t)N * NDIM;
  float* g2 = g1 + (size_t)N * NDIM;
  ushort* hB0 = (ushort*)(g2 + (size_t)N * NDIM);
  ushort* hB1 = hB0 + (size_t)N * NDIM;
  ushort* hB2 = hB1 + (size_t)N * NDIM;

  int chunk = (E + NCHK - 1) / NCHK;
  int nb = (N + SCAN_ELEMS - 1) / SCAN_ELEMS;
  int nblk = (N + 255) / 256;

  transpose_kernel<<<112, 256, 0, stream>>>(fw, rootw, lin1, lin2, fwT, wrT, w1T, w2T);
  convx_kernel<<<(N * 16 + 255) / 256, 256, 0, stream>>>(x, (uint*)hB0, N * 16);
  hist_kernel<<<dim3(NCHK, NGRP), 256, 0, stream>>>(src, dst, Hd, Hs, E, N, chunk);
  degsum_kernel<<<nblk, 256, 0, stream>>>(Hd, Hs, deg_d, deg_s, N);
  scan_partial<<<dim3(nb, 2), 256, 0, stream>>>(deg_d, deg_s, bsum, N, nb);
  scan_bsum<<<1, 256, 0, stream>>>(bsum, nb);
  scan_final<<<dim3(nb, 2), 256, 0, stream>>>(deg_d, deg_s, bsum, row_d, row_s, N, nb);
  cursor_kernel<<<nblk, 256, 0, stream>>>(Hd, Hs, row_d, row_s, N);
  scatter_kernel<<<dim3(NCHK, NGRP), 256, 0, stream>>>(src, dst, Hd, Hs,
                                                       col_d, col_s, E, N, chunk);

  int ab = (N + 3) / 4;
  int tgrid = (N + 63) / 64;
  const float*  hbufs[4]  = {x, h1, h2, h3};
  const ushort* hBbufs[3] = {hB0, hB1, hB2};
  for (int l = 0; l < 3; ++l) {
    agg2b_kernel<<<dim3(ab, 2), 256, 0, stream>>>(hBbufs[l], row_d, col_d, g1,
                                                  row_s, col_s, g2, N);
    ushort* hbnext = (l < 2) ? (ushort*)hBbufs[l + 1] : (ushort*)nullptr;
    combine_kernel<<<tgrid, 256, 0, stream>>>(hbufs[l], g1, g2,
                                              wrT + (size_t)l * 4096,
                                              w1T + (size_t)l * 4096,
                                              w2T + (size_t)l * 4096,
                                              rootb + (size_t)l * 64,
                                              (float*)hbufs[l + 1], hbnext, N);
  }
  final_kernel<<<tgrid, 256, 0, stream>>>(x, h1, h2, h3, fwT, fb, out, N);
}